// Round 1
// baseline (1038.544 us; speedup 1.0000x reference)
//
#include <hip/hip_runtime.h>
#include <hip/hip_bf16.h>

// ---------------------------------------------------------------------------
// MHSA fp32 baseline: B=2, S=2048, D=1024, H=16, HD=64
//   k1: qkv = x @ W_qkv + b_qkv            [4096, 3072]
//   k2: flash attention per (b,h,qtile)    -> attn [4096, 1024] ([B,S,H*HD])
//   k3: out = attn @ W_out + b_out         [4096, 1024]
// ---------------------------------------------------------------------------

#define BM 128
#define BN 128
#define BK 16
#define LDA 132   // BM + 4 pad (bank spread, keeps 16B alignment: 132*4=528)
#define LDB 132

__global__ __launch_bounds__(256) void gemm_bias(
    const float* __restrict__ A,   // [M,K] row-major
    const float* __restrict__ W,   // [K,N] row-major
    const float* __restrict__ bias,// [N]
    float* __restrict__ C,         // [M,N]
    int M, int N, int K)
{
    __shared__ float As[BK][LDA];  // A-tile transposed: As[k][m]
    __shared__ float Bs[BK][LDB];  // Bs[k][n]

    const int tid = threadIdx.x;
    const int tx = tid & 15;       // 0..15 -> col block
    const int ty = tid >> 4;       // 0..15 -> row block
    const int m0 = blockIdx.y * BM;
    const int n0 = blockIdx.x * BN;

    // A staging: 4 threads per row, float4 each; rows ra and ra+64
    const int ra  = tid >> 2;          // 0..63
    const int ka0 = (tid & 3) * 4;     // 0,4,8,12
    // B staging: 16 threads per k-row, float4 each; col halves
    const int kb  = tid >> 4;          // 0..15
    const int nb0 = (tid & 15) * 4;    // 0..60

    float acc[8][8];
#pragma unroll
    for (int i = 0; i < 8; ++i)
#pragma unroll
        for (int j = 0; j < 8; ++j) acc[i][j] = 0.0f;

    for (int k0 = 0; k0 < K; k0 += BK) {
        // prefetch globals into registers before the barrier
        float4 a0 = *(const float4*)&A[(size_t)(m0 + ra)      * K + k0 + ka0];
        float4 a1 = *(const float4*)&A[(size_t)(m0 + ra + 64) * K + k0 + ka0];
        float4 b0 = *(const float4*)&W[(size_t)(k0 + kb) * N + n0 + nb0];
        float4 b1 = *(const float4*)&W[(size_t)(k0 + kb) * N + n0 + nb0 + 64];

        __syncthreads();   // previous iteration's LDS reads done

        As[ka0 + 0][ra] = a0.x;  As[ka0 + 1][ra] = a0.y;
        As[ka0 + 2][ra] = a0.z;  As[ka0 + 3][ra] = a0.w;
        As[ka0 + 0][ra + 64] = a1.x;  As[ka0 + 1][ra + 64] = a1.y;
        As[ka0 + 2][ra + 64] = a1.z;  As[ka0 + 3][ra + 64] = a1.w;
        *(float4*)&Bs[kb][nb0]      = b0;
        *(float4*)&Bs[kb][nb0 + 64] = b1;

        __syncthreads();

#pragma unroll
        for (int kk = 0; kk < BK; ++kk) {
            float4 x0 = *(const float4*)&As[kk][8 * ty];
            float4 x1 = *(const float4*)&As[kk][8 * ty + 4];
            float4 y0 = *(const float4*)&Bs[kk][8 * tx];
            float4 y1 = *(const float4*)&Bs[kk][8 * tx + 4];
            float xa[8] = {x0.x, x0.y, x0.z, x0.w, x1.x, x1.y, x1.z, x1.w};
            float yb[8] = {y0.x, y0.y, y0.z, y0.w, y1.x, y1.y, y1.z, y1.w};
#pragma unroll
            for (int i = 0; i < 8; ++i)
#pragma unroll
                for (int j = 0; j < 8; ++j)
                    acc[i][j] = fmaf(xa[i], yb[j], acc[i][j]);
        }
    }

    // epilogue: bias + store (float4)
#pragma unroll
    for (int i = 0; i < 8; ++i) {
        const size_t row = (size_t)(m0 + 8 * ty + i);
#pragma unroll
        for (int j4 = 0; j4 < 8; j4 += 4) {
            const int col = n0 + 8 * tx + j4;
            float4 o;
            o.x = acc[i][j4 + 0] + bias[col + 0];
            o.y = acc[i][j4 + 1] + bias[col + 1];
            o.z = acc[i][j4 + 2] + bias[col + 2];
            o.w = acc[i][j4 + 3] + bias[col + 3];
            *(float4*)&C[row * N + col] = o;
        }
    }
}

// ---------------------------------------------------------------------------
// Flash attention, fp32. Block = 256 threads handles one (b,h) and a 64-row
// Q tile; iterates 32 K/V tiles of 64. 16x16 thread grid, 4x4 micro-tile.
// Row softmax state (m,l) kept in registers, replicated across the 16 lanes
// that share a row group; reduced with __shfl_xor over the low 4 lane bits.
// ---------------------------------------------------------------------------
#define LDT 68    // 64 + 4 pad; 68*4 = 272 bytes, 16B aligned rows

__global__ __launch_bounds__(256) void attn_kernel(
    const float* __restrict__ qkv,   // [B*S, 3072]; q at h*64, k +1024, v +2048
    float* __restrict__ out)         // [B*S, 1024] = [B,S,H*HD]
{
    __shared__ float QsT[64][LDT];   // QsT[d][r] = q[r][d] * 0.125
    __shared__ float Kts[64][LDT];   // Kts[d][t] = k[t][d]
    __shared__ float Vs [64][LDT];   // Vs[t][d]
    __shared__ float SsT[64][LDT];   // SsT[t][r] = P[r][t]

    const int tid = threadIdx.x;
    const int tx = tid & 15;         // col block (0..15)
    const int ty = tid >> 4;         // row block (0..15)
    const int s0 = blockIdx.x * 64;
    const int bh = blockIdx.y;       // b*16 + h
    const int b = bh >> 4, h = bh & 15;

    const float* base = qkv + (size_t)(b * 2048) * 3072 + h * 64;

    const int lr  = tid >> 2;        // 0..63 staging row
    const int ld0 = (tid & 3) * 16;  // 0,16,32,48

    // --- load Q tile (scaled), transposed ---
#pragma unroll
    for (int u = 0; u < 4; ++u) {
        float4 f = *(const float4*)(base + (size_t)(s0 + lr) * 3072 + ld0 + 4 * u);
        QsT[ld0 + 4 * u + 0][lr] = f.x * 0.125f;
        QsT[ld0 + 4 * u + 1][lr] = f.y * 0.125f;
        QsT[ld0 + 4 * u + 2][lr] = f.z * 0.125f;
        QsT[ld0 + 4 * u + 3][lr] = f.w * 0.125f;
    }

    float m_i[4], l_i[4], O[4][4];
#pragma unroll
    for (int i = 0; i < 4; ++i) {
        m_i[i] = -1e30f;
        l_i[i] = 0.0f;
#pragma unroll
        for (int j = 0; j < 4; ++j) O[i][j] = 0.0f;
    }

    const float* kbase = base + 1024;
    const float* vbase = base + 2048;

    for (int t0 = 0; t0 < 2048; t0 += 64) {
        __syncthreads();  // previous PV reads (and Q writes, 1st iter) done

        // --- stage K (transposed) and V ---
#pragma unroll
        for (int u = 0; u < 4; ++u) {
            float4 f = *(const float4*)(kbase + (size_t)(t0 + lr) * 3072 + ld0 + 4 * u);
            Kts[ld0 + 4 * u + 0][lr] = f.x;
            Kts[ld0 + 4 * u + 1][lr] = f.y;
            Kts[ld0 + 4 * u + 2][lr] = f.z;
            Kts[ld0 + 4 * u + 3][lr] = f.w;
            float4 g = *(const float4*)(vbase + (size_t)(t0 + lr) * 3072 + ld0 + 4 * u);
            *(float4*)&Vs[lr][ld0 + 4 * u] = g;
        }
        __syncthreads();

        // --- S tile: s[i][j] = sum_d q(4ty+i,d)*k(4tx+j,d), q pre-scaled ---
        float s[4][4];
#pragma unroll
        for (int i = 0; i < 4; ++i)
#pragma unroll
            for (int j = 0; j < 4; ++j) s[i][j] = 0.0f;
#pragma unroll 8
        for (int k = 0; k < 64; ++k) {
            float4 qv = *(const float4*)&QsT[k][4 * ty];
            float4 kv = *(const float4*)&Kts[k][4 * tx];
            float qa[4] = {qv.x, qv.y, qv.z, qv.w};
            float ka[4] = {kv.x, kv.y, kv.z, kv.w};
#pragma unroll
            for (int i = 0; i < 4; ++i)
#pragma unroll
                for (int j = 0; j < 4; ++j)
                    s[i][j] = fmaf(qa[i], ka[j], s[i][j]);
        }

        // --- online softmax per row (16 lanes share a row group) ---
#pragma unroll
        for (int i = 0; i < 4; ++i) {
            float mx = s[i][0];
            mx = fmaxf(mx, s[i][1]); mx = fmaxf(mx, s[i][2]); mx = fmaxf(mx, s[i][3]);
            mx = fmaxf(mx, __shfl_xor(mx, 1));
            mx = fmaxf(mx, __shfl_xor(mx, 2));
            mx = fmaxf(mx, __shfl_xor(mx, 4));
            mx = fmaxf(mx, __shfl_xor(mx, 8));
            const float mnew = fmaxf(m_i[i], mx);
            const float alpha = __expf(m_i[i] - mnew);
            float p[4], rs = 0.0f;
#pragma unroll
            for (int j = 0; j < 4; ++j) {
                p[j] = __expf(s[i][j] - mnew);
                rs += p[j];
            }
            rs += __shfl_xor(rs, 1);
            rs += __shfl_xor(rs, 2);
            rs += __shfl_xor(rs, 4);
            rs += __shfl_xor(rs, 8);
            l_i[i] = l_i[i] * alpha + rs;
            m_i[i] = mnew;
#pragma unroll
            for (int j = 0; j < 4; ++j) {
                O[i][j] *= alpha;
                SsT[4 * tx + j][4 * ty + i] = p[j];
            }
        }
        __syncthreads();

        // --- O += P @ V ---
#pragma unroll 8
        for (int t = 0; t < 64; ++t) {
            float4 pv = *(const float4*)&SsT[t][4 * ty];
            float4 vv = *(const float4*)&Vs[t][4 * tx];
            float pa[4] = {pv.x, pv.y, pv.z, pv.w};
            float va[4] = {vv.x, vv.y, vv.z, vv.w};
#pragma unroll
            for (int i = 0; i < 4; ++i)
#pragma unroll
                for (int j = 0; j < 4; ++j)
                    O[i][j] = fmaf(pa[i], va[j], O[i][j]);
        }
    }

    // --- epilogue: normalize and store [B,S,H*HD] ---
#pragma unroll
    for (int i = 0; i < 4; ++i) {
        const float inv = 1.0f / l_i[i];
        const size_t row = (size_t)(b * 2048 + s0 + 4 * ty + i);
        float4 o;
        o.x = O[i][0] * inv; o.y = O[i][1] * inv;
        o.z = O[i][2] * inv; o.w = O[i][3] * inv;
        *(float4*)&out[row * 1024 + h * 64 + 4 * tx] = o;
    }
}

extern "C" void kernel_launch(void* const* d_in, const int* in_sizes, int n_in,
                              void* d_out, int out_size, void* d_ws, size_t ws_size,
                              hipStream_t stream) {
    const float* x     = (const float*)d_in[0];  // [2,2048,1024]
    const float* W_qkv = (const float*)d_in[1];  // [1024,3072]
    const float* b_qkv = (const float*)d_in[2];  // [3072]
    const float* W_out = (const float*)d_in[3];  // [1024,1024]
    const float* b_out = (const float*)d_in[4];  // [1024]
    float* out = (float*)d_out;                  // [2,2048,1024]

    float* qkv   = (float*)d_ws;                                  // 48 MB
    float* attnb = (float*)((char*)d_ws + (size_t)4096 * 3072 * 4); // +16 MB

    // k1: qkv = x @ W_qkv + b_qkv
    dim3 g1(3072 / BN, 4096 / BM);
    gemm_bias<<<g1, 256, 0, stream>>>(x, W_qkv, b_qkv, qkv, 4096, 3072, 1024);

    // k2: flash attention
    dim3 g2(2048 / 64, 32);  // (q tiles, B*H)
    attn_kernel<<<g2, 256, 0, stream>>>(qkv, attnb);

    // k3: out = attn @ W_out + b_out
    dim3 g3(1024 / BN, 4096 / BM);
    gemm_bias<<<g3, 256, 0, stream>>>(attnb, W_out, b_out, out, 4096, 1024, 1024);
}

// Round 2
// 328.149 us; speedup vs baseline: 3.1649x; 3.1649x over previous
//
#include <hip/hip_runtime.h>

// ---------------------------------------------------------------------------
// MHSA bf16-MFMA pipeline: B=2, S=2048, D=1024, H=16, HD=64
//   p1: x (f32) -> x_bf (bf16)
//   p2: W_qkv [1024,3072] f32 -> Wqkv_t [3072,1024] bf16   (transpose+cvt)
//   p3: W_out [1024,1024] f32 -> Wout_t [1024,1024] bf16
//   k1: qkv_bf = x_bf @ Wqkv_t^T + b_qkv   (bf16 out, fp32 accum/bias)
//   p4: vT[bh][d][t] bf16  (V transposed per head)
//   k2: flash attention (MFMA 16x16x32), attn_b bf16 [4096,1024]
//   k3: out = attn_b @ Wout_t^T + b_out    (fp32 out)
// MFMA frag layouts (m89/m91/m120-verified):
//   A[m=lane&15][k=quad*8+j], B[k=quad*8+j][n=lane&15],
//   C col=lane&15, row=quad*4+reg
// ---------------------------------------------------------------------------

typedef short bf16x8 __attribute__((ext_vector_type(8)));
typedef float f32x4 __attribute__((ext_vector_type(4)));

__device__ __forceinline__ unsigned short f2bf(float f) {
  unsigned u = __float_as_uint(f);
  u = (u + 0x7fffu + ((u >> 16) & 1u)) >> 16;   // round-to-nearest-even
  return (unsigned short)u;
}

// --- p1: elementwise f32 -> bf16 (8 elems/thread) --------------------------
__global__ __launch_bounds__(256) void cvt_f32_bf16(
    const float* __restrict__ in, unsigned short* __restrict__ out, int n)
{
  const int i = (blockIdx.x * 256 + threadIdx.x) * 8;
  if (i >= n) return;
  float4 f0 = *(const float4*)(in + i);
  float4 f1 = *(const float4*)(in + i + 4);
  union { unsigned short u[8]; uint4 v; } pk;
  pk.u[0] = f2bf(f0.x); pk.u[1] = f2bf(f0.y); pk.u[2] = f2bf(f0.z); pk.u[3] = f2bf(f0.w);
  pk.u[4] = f2bf(f1.x); pk.u[5] = f2bf(f1.y); pk.u[6] = f2bf(f1.z); pk.u[7] = f2bf(f1.w);
  *(uint4*)(out + i) = pk.v;
}

// --- p2/p3: transpose + convert: in f32 [R][C] -> out bf16 [C][R] ----------
__global__ __launch_bounds__(256) void transpose_cvt(
    const float* __restrict__ in, unsigned short* __restrict__ out, int R, int C)
{
  __shared__ float tile[64][65];
  const int tid = threadIdx.x;
  const int r0 = blockIdx.y * 64, c0 = blockIdx.x * 64;
  {
    const int rr = tid >> 4;          // 0..15
    const int cc = (tid & 15) * 4;
#pragma unroll
    for (int it = 0; it < 4; ++it) {
      float4 f = *(const float4*)&in[(size_t)(r0 + rr + 16 * it) * C + c0 + cc];
      tile[rr + 16 * it][cc + 0] = f.x;
      tile[rr + 16 * it][cc + 1] = f.y;
      tile[rr + 16 * it][cc + 2] = f.z;
      tile[rr + 16 * it][cc + 3] = f.w;
    }
  }
  __syncthreads();
  {
    const int cr = tid >> 2;          // 0..63 (output row = original col)
    const int rk = (tid & 3) * 16;    // 16 original-rows per thread
    union { unsigned short u[16]; uint4 v[2]; } pk;
#pragma unroll
    for (int j = 0; j < 16; ++j) pk.u[j] = f2bf(tile[rk + j][cr]);
    uint4* dst = (uint4*)&out[(size_t)(c0 + cr) * R + r0 + rk];
    dst[0] = pk.v[0];
    dst[1] = pk.v[1];
  }
}

// --- p4: V transpose: qkv bf16 -> vT[bh][64 d][2048 t] ---------------------
__global__ __launch_bounds__(256) void transpose_v(
    const unsigned short* __restrict__ qkv, unsigned short* __restrict__ vT)
{
  __shared__ unsigned int tile[64][33];   // [t][d-pair]
  const int tid = threadIdx.x;
  const int bh = blockIdx.y, b = bh >> 4, h = bh & 15;
  const int t0 = blockIdx.x * 64;
  const unsigned short* src = qkv + (size_t)(b * 2048) * 3072 + 2048 + h * 64;
  {
    const int tr = tid >> 2;          // 0..63 key row
    const int dc = (tid & 3) * 16;    // d offset
    uint4 f = *(const uint4*)&src[(size_t)(t0 + tr) * 3072 + dc];
    uint4 g = *(const uint4*)&src[(size_t)(t0 + tr) * 3072 + dc + 8];
    const int d2 = dc >> 1;
    tile[tr][d2 + 0] = f.x; tile[tr][d2 + 1] = f.y;
    tile[tr][d2 + 2] = f.z; tile[tr][d2 + 3] = f.w;
    tile[tr][d2 + 4] = g.x; tile[tr][d2 + 5] = g.y;
    tile[tr][d2 + 6] = g.z; tile[tr][d2 + 7] = g.w;
  }
  __syncthreads();
  {
    const int dr = tid >> 2;          // 0..63 output row (d)
    const int tc = (tid & 3) * 16;    // t chunk
    const int hi = dr & 1;
    union { unsigned short u[16]; uint4 v[2]; } pk;
#pragma unroll
    for (int j = 0; j < 16; ++j) {
      unsigned int w = tile[tc + j][dr >> 1];
      pk.u[j] = (unsigned short)(hi ? (w >> 16) : (w & 0xffffu));
    }
    uint4* dst = (uint4*)&vT[((size_t)bh * 64 + dr) * 2048 + t0 + tc];
    dst[0] = pk.v[0];
    dst[1] = pk.v[1];
  }
}

// --- k1/k3: GEMM C[M,N] = A[M,K](bf16) @ Bt[N,K]^T(bf16) + bias ------------
template <int OUT_BF16>
__global__ __launch_bounds__(256) void gemm_mfma(
    const unsigned short* __restrict__ A,
    const unsigned short* __restrict__ Bt,
    const float* __restrict__ bias,
    void* __restrict__ Cout, int M, int N, int K)
{
  __shared__ unsigned short As[128][40];   // rows of A tile, pad 32->40
  __shared__ unsigned short Bs[128][40];   // rows of Bt tile
  const int tid = threadIdx.x;
  const int wave = tid >> 6, lane = tid & 63;
  const int l16 = lane & 15, quad = lane >> 4;
  const int m0 = blockIdx.y * 128, n0 = blockIdx.x * 128;
  const int wm = (wave & 1) * 64, wn = (wave >> 1) * 64;

  const int ra = tid >> 2;          // 0..63; handles rows ra and ra+64
  const int sa = (tid & 3) * 8;     // k-element offset (16B chunks)

  f32x4 acc[4][4] = {};

  for (int k0 = 0; k0 < K; k0 += 32) {
    uint4 a0 = *(const uint4*)&A [(size_t)(m0 + ra)      * K + k0 + sa];
    uint4 a1 = *(const uint4*)&A [(size_t)(m0 + ra + 64) * K + k0 + sa];
    uint4 b0 = *(const uint4*)&Bt[(size_t)(n0 + ra)      * K + k0 + sa];
    uint4 b1 = *(const uint4*)&Bt[(size_t)(n0 + ra + 64) * K + k0 + sa];
    __syncthreads();
    *(uint4*)&As[ra][sa]      = a0;
    *(uint4*)&As[ra + 64][sa] = a1;
    *(uint4*)&Bs[ra][sa]      = b0;
    *(uint4*)&Bs[ra + 64][sa] = b1;
    __syncthreads();

    bf16x8 af[4], bfr[4];
#pragma unroll
    for (int mi = 0; mi < 4; ++mi)
      af[mi] = *(const bf16x8*)&As[wm + 16 * mi + l16][quad * 8];
#pragma unroll
    for (int ni = 0; ni < 4; ++ni)
      bfr[ni] = *(const bf16x8*)&Bs[wn + 16 * ni + l16][quad * 8];
#pragma unroll
    for (int mi = 0; mi < 4; ++mi)
#pragma unroll
      for (int ni = 0; ni < 4; ++ni)
        acc[mi][ni] = __builtin_amdgcn_mfma_f32_16x16x32_bf16(
            af[mi], bfr[ni], acc[mi][ni], 0, 0, 0);
  }

#pragma unroll
  for (int ni = 0; ni < 4; ++ni) {
    const int col = n0 + wn + 16 * ni + l16;
    const float bv = bias[col];
#pragma unroll
    for (int mi = 0; mi < 4; ++mi) {
#pragma unroll
      for (int i = 0; i < 4; ++i) {
        const int row = m0 + wm + 16 * mi + quad * 4 + i;
        const float v = acc[mi][ni][i] + bv;
        if (OUT_BF16)
          ((unsigned short*)Cout)[(size_t)row * N + col] = f2bf(v);
        else
          ((float*)Cout)[(size_t)row * N + col] = v;
      }
    }
  }
}

// --- k2: flash attention, MFMA 16x16x32 bf16 -------------------------------
// Block = 4 waves; wave w owns Q rows [bx*128 + 32w, +32). No __syncthreads:
// Q/K frags read directly from qkv (bf16, L2/L3-resident), V frags from vT.
// Only P does a wave-private LDS round-trip (C-layout -> A-layout).
__global__ __launch_bounds__(256) void attn_mfma(
    const unsigned short* __restrict__ qkv,
    const unsigned short* __restrict__ vT,
    unsigned short* __restrict__ attn_out)
{
  __shared__ unsigned short P_lds[4][32][72];   // per-wave P, pad 64->72
  const int tid = threadIdx.x;
  const int wave = tid >> 6, lane = tid & 63;
  const int l16 = lane & 15, quad = lane >> 4;
  const int bh = blockIdx.y, b = bh >> 4, h = bh & 15;
  const int s0 = blockIdx.x * 128 + wave * 32;

  const unsigned short* qb = qkv + (size_t)(b * 2048) * 3072 + h * 64;
  const unsigned short* kb = qb + 1024;
  const unsigned short* vb = vT + (size_t)bh * 64 * 2048;

  // Q frags: 2 M-strips (16 rows) x 2 K-steps (d halves)
  bf16x8 qf[2][2];
#pragma unroll
  for (int mt = 0; mt < 2; ++mt)
#pragma unroll
    for (int ks = 0; ks < 2; ++ks)
      qf[mt][ks] = *(const bf16x8*)&qb[(size_t)(s0 + 16 * mt + l16) * 3072 + 32 * ks + quad * 8];

  f32x4 Of[2][4] = {};
  float m_r[2][4], l_r[2][4];
#pragma unroll
  for (int mt = 0; mt < 2; ++mt)
#pragma unroll
    for (int i = 0; i < 4; ++i) { m_r[mt][i] = -1e30f; l_r[mt][i] = 0.0f; }

  const float SC = 0.125f * 1.44269504f;   // log2(e)/sqrt(HD)

  for (int t0 = 0; t0 < 2048; t0 += 64) {
    // ---- S = Q K^T (raw logits, fp32) ----
    f32x4 sf[2][4];
#pragma unroll
    for (int nt = 0; nt < 4; ++nt) {
      const size_t krow = (size_t)(t0 + 16 * nt + l16) * 3072;
      bf16x8 kf0 = *(const bf16x8*)&kb[krow + quad * 8];
      bf16x8 kf1 = *(const bf16x8*)&kb[krow + 32 + quad * 8];
#pragma unroll
      for (int mt = 0; mt < 2; ++mt) {
        f32x4 c = {0.0f, 0.0f, 0.0f, 0.0f};
        c = __builtin_amdgcn_mfma_f32_16x16x32_bf16(qf[mt][0], kf0, c, 0, 0, 0);
        c = __builtin_amdgcn_mfma_f32_16x16x32_bf16(qf[mt][1], kf1, c, 0, 0, 0);
        sf[mt][nt] = c;
      }
    }

    // ---- online softmax (base-2 domain, scale folded) ----
#pragma unroll
    for (int mt = 0; mt < 2; ++mt) {
#pragma unroll
      for (int i = 0; i < 4; ++i) {
        float mx = fmaxf(fmaxf(sf[mt][0][i], sf[mt][1][i]),
                         fmaxf(sf[mt][2][i], sf[mt][3][i]));
        mx = fmaxf(mx, __shfl_xor(mx, 1));
        mx = fmaxf(mx, __shfl_xor(mx, 2));
        mx = fmaxf(mx, __shfl_xor(mx, 4));
        mx = fmaxf(mx, __shfl_xor(mx, 8));
        const float mnew = fmaxf(m_r[mt][i], mx * SC);
        const float alpha = __builtin_amdgcn_exp2f(m_r[mt][i] - mnew);
        m_r[mt][i] = mnew;
        float rs = 0.0f;
#pragma unroll
        for (int nt = 0; nt < 4; ++nt) {
          const float p = __builtin_amdgcn_exp2f(sf[mt][nt][i] * SC - mnew);
          sf[mt][nt][i] = p;
          rs += p;
        }
        rs += __shfl_xor(rs, 1);
        rs += __shfl_xor(rs, 2);
        rs += __shfl_xor(rs, 4);
        rs += __shfl_xor(rs, 8);
        l_r[mt][i] = l_r[mt][i] * alpha + rs;
#pragma unroll
        for (int nd = 0; nd < 4; ++nd) Of[mt][nd][i] *= alpha;
      }
    }

    // ---- P: C-layout regs -> LDS (bf16) ----
#pragma unroll
    for (int mt = 0; mt < 2; ++mt)
#pragma unroll
      for (int nt = 0; nt < 4; ++nt)
#pragma unroll
        for (int i = 0; i < 4; ++i)
          P_lds[wave][16 * mt + quad * 4 + i][16 * nt + l16] = f2bf(sf[mt][nt][i]);

    // ---- O += P V ----
#pragma unroll
    for (int ks = 0; ks < 2; ++ks) {
      bf16x8 pf[2];
#pragma unroll
      for (int mt = 0; mt < 2; ++mt)
        pf[mt] = *(const bf16x8*)&P_lds[wave][16 * mt + l16][32 * ks + quad * 8];
#pragma unroll
      for (int nd = 0; nd < 4; ++nd) {
        bf16x8 vf = *(const bf16x8*)&vb[(size_t)(16 * nd + l16) * 2048 + t0 + 32 * ks + quad * 8];
#pragma unroll
        for (int mt = 0; mt < 2; ++mt)
          Of[mt][nd] = __builtin_amdgcn_mfma_f32_16x16x32_bf16(pf[mt], vf, Of[mt][nd], 0, 0, 0);
      }
    }
  }

  // ---- epilogue: normalize, store bf16 [b][s][h*64+d] ----
#pragma unroll
  for (int mt = 0; mt < 2; ++mt) {
#pragma unroll
    for (int i = 0; i < 4; ++i) {
      const float inv = 1.0f / l_r[mt][i];
      const size_t row = (size_t)(b * 2048 + s0 + 16 * mt + quad * 4 + i);
#pragma unroll
      for (int nd = 0; nd < 4; ++nd)
        attn_out[row * 1024 + h * 64 + 16 * nd + l16] = f2bf(Of[mt][nd][i] * inv);
    }
  }
}

extern "C" void kernel_launch(void* const* d_in, const int* in_sizes, int n_in,
                              void* d_out, int out_size, void* d_ws, size_t ws_size,
                              hipStream_t stream) {
  const float* x     = (const float*)d_in[0];  // [2,2048,1024]
  const float* W_qkv = (const float*)d_in[1];  // [1024,3072]
  const float* b_qkv = (const float*)d_in[2];  // [3072]
  const float* W_out = (const float*)d_in[3];  // [1024,1024]
  const float* b_out = (const float*)d_in[4];  // [1024]
  float* out = (float*)d_out;                  // [2,2048,1024]

  char* ws = (char*)d_ws;
  unsigned short* x_bf   = (unsigned short*)(ws);              //  8.0 MB
  unsigned short* Wqkv_t = (unsigned short*)(ws + 8388608);    //  6.0 MB
  unsigned short* Wout_t = (unsigned short*)(ws + 14680064);   //  2.0 MB
  unsigned short* qkv_bf = (unsigned short*)(ws + 16777216);   // 24.0 MB
  unsigned short* vT     = (unsigned short*)(ws + 41943040);   //  8.0 MB
  unsigned short* attn_b = (unsigned short*)(ws + 50331648);   //  8.0 MB

  cvt_f32_bf16<<<2048, 256, 0, stream>>>(x, x_bf, 4096 * 1024);
  transpose_cvt<<<dim3(48, 16), 256, 0, stream>>>(W_qkv, Wqkv_t, 1024, 3072);
  transpose_cvt<<<dim3(16, 16), 256, 0, stream>>>(W_out, Wout_t, 1024, 1024);

  gemm_mfma<1><<<dim3(24, 32), 256, 0, stream>>>(x_bf, Wqkv_t, b_qkv, qkv_bf,
                                                 4096, 3072, 1024);
  transpose_v<<<dim3(32, 32), 256, 0, stream>>>(qkv_bf, vT);
  attn_mfma<<<dim3(16, 32), 256, 0, stream>>>(qkv_bf, vT, attn_b);
  gemm_mfma<0><<<dim3(8, 32), 256, 0, stream>>>(attn_b, Wout_t, b_out, out,
                                                4096, 1024, 1024);
}

// Round 3
// 268.451 us; speedup vs baseline: 3.8687x; 1.2224x over previous
//
#include <hip/hip_runtime.h>

// ---------------------------------------------------------------------------
// MHSA bf16-MFMA pipeline v3: B=2, S=2048, D=1024, H=16, HD=64
//   p1: x f32 -> bf16;  p2/p3: W transposes -> bf16 [N][K]
//   k1: qkv GEMM (global_load_lds staging); Q,K -> qkv_bf row-major,
//       V -> vT[bh][d][t] directly in the epilogue
//   k2: flash attention, S^T orientation, no-max softmax, 2-way t-split
//   k3: out GEMM -> f32
// Frag layouts (m89/m91 verified): A[m=l16][k=quad*8+j], B[k=quad*8+j][n=l16],
// C: col=l16, row=quad*4+reg.
// ---------------------------------------------------------------------------

typedef short bf16x8 __attribute__((ext_vector_type(8)));
typedef float f32x4 __attribute__((ext_vector_type(4)));

__device__ __forceinline__ unsigned short f2bf(float f) {   // RNE
  unsigned u = __float_as_uint(f);
  u = (u + 0x7fffu + ((u >> 16) & 1u)) >> 16;
  return (unsigned short)u;
}
// two f32 -> packed bf16x2 (round-half-up; fine for P/attn magnitudes)
__device__ __forceinline__ unsigned pack_bf2(float lo, float hi) {
  unsigned a = __float_as_uint(lo) + 0x8000u;
  unsigned b = __float_as_uint(hi) + 0x8000u;
  return __builtin_amdgcn_perm(b, a, 0x07060302);
}
__device__ __forceinline__ void load_lds16(const unsigned short* g, unsigned short* l) {
  __builtin_amdgcn_global_load_lds(
      (const __attribute__((address_space(1))) void*)g,
      (__attribute__((address_space(3))) void*)l, 16, 0, 0);
}

// --- p1: f32 -> bf16 -------------------------------------------------------
__global__ __launch_bounds__(256) void cvt_f32_bf16(
    const float* __restrict__ in, unsigned short* __restrict__ out, int n)
{
  const int i = (blockIdx.x * 256 + threadIdx.x) * 8;
  if (i >= n) return;
  float4 f0 = *(const float4*)(in + i);
  float4 f1 = *(const float4*)(in + i + 4);
  union { unsigned short u[8]; uint4 v; } pk;
  pk.u[0] = f2bf(f0.x); pk.u[1] = f2bf(f0.y); pk.u[2] = f2bf(f0.z); pk.u[3] = f2bf(f0.w);
  pk.u[4] = f2bf(f1.x); pk.u[5] = f2bf(f1.y); pk.u[6] = f2bf(f1.z); pk.u[7] = f2bf(f1.w);
  *(uint4*)(out + i) = pk.v;
}

// --- p2/p3: transpose+cvt: f32 [R][C] -> bf16 [C][R] -----------------------
__global__ __launch_bounds__(256) void transpose_cvt(
    const float* __restrict__ in, unsigned short* __restrict__ out, int R, int C)
{
  __shared__ float tile[64][65];
  const int tid = threadIdx.x;
  const int r0 = blockIdx.y * 64, c0 = blockIdx.x * 64;
  {
    const int rr = tid >> 4;
    const int cc = (tid & 15) * 4;
#pragma unroll
    for (int it = 0; it < 4; ++it) {
      float4 f = *(const float4*)&in[(size_t)(r0 + rr + 16 * it) * C + c0 + cc];
      tile[rr + 16 * it][cc + 0] = f.x;
      tile[rr + 16 * it][cc + 1] = f.y;
      tile[rr + 16 * it][cc + 2] = f.z;
      tile[rr + 16 * it][cc + 3] = f.w;
    }
  }
  __syncthreads();
  {
    const int cr = tid >> 2;
    const int rk = (tid & 3) * 16;
    union { unsigned short u[16]; uint4 v[2]; } pk;
#pragma unroll
    for (int j = 0; j < 16; ++j) pk.u[j] = f2bf(tile[rk + j][cr]);
    uint4* dst = (uint4*)&out[(size_t)(c0 + cr) * R + r0 + rk];
    dst[0] = pk.v[0];
    dst[1] = pk.v[1];
  }
}

// --- k1/k3: GEMM C = A[M,K] @ Bt[N,K]^T + bias, m97-style staging ----------
// MODE 0: f32 out.  MODE 1: bf16; cols<2048 -> qkv row-major, cols>=2048 (V)
// transposed into vT[bh][d][t].
template <int MODE>
__global__ __launch_bounds__(256) void gemm_mfma(
    const unsigned short* __restrict__ A,
    const unsigned short* __restrict__ Bt,
    const float* __restrict__ bias,
    void* __restrict__ Cout, unsigned short* __restrict__ vT,
    int M, int N, int K)
{
  __shared__ unsigned short As[128][32];   // contiguous (global_load_lds)
  __shared__ unsigned short Bs[128][32];
  const int tid = threadIdx.x;
  const int wave = tid >> 6, lane = tid & 63;
  const int l16 = lane & 15, quad = lane >> 4;
  const int m0 = blockIdx.y * 128, n0 = blockIdx.x * 128;
  const int wm = (wave & 1) * 64, wn = (wave >> 1) * 64;
  const int lr = lane >> 2;            // row within 16-row group
  const int lc = (lane & 3) * 8;       // k-chunk (16B)

  f32x4 acc[4][4] = {};

  for (int k0 = 0; k0 < K; k0 += 32) {
    __syncthreads();
    load_lds16(&A [(size_t)(m0 + 16 * wave + lr) * K + k0 + lc],      &As[16 * wave][0]);
    load_lds16(&A [(size_t)(m0 + 64 + 16 * wave + lr) * K + k0 + lc], &As[64 + 16 * wave][0]);
    load_lds16(&Bt[(size_t)(n0 + 16 * wave + lr) * K + k0 + lc],      &Bs[16 * wave][0]);
    load_lds16(&Bt[(size_t)(n0 + 64 + 16 * wave + lr) * K + k0 + lc], &Bs[64 + 16 * wave][0]);
    __syncthreads();

    bf16x8 af[4], bfr[4];
#pragma unroll
    for (int mi = 0; mi < 4; ++mi)
      af[mi] = *(const bf16x8*)&As[wm + 16 * mi + l16][quad * 8];
#pragma unroll
    for (int ni = 0; ni < 4; ++ni)
      bfr[ni] = *(const bf16x8*)&Bs[wn + 16 * ni + l16][quad * 8];
#pragma unroll
    for (int mi = 0; mi < 4; ++mi)
#pragma unroll
      for (int ni = 0; ni < 4; ++ni)
        acc[mi][ni] = __builtin_amdgcn_mfma_f32_16x16x32_bf16(
            af[mi], bfr[ni], acc[mi][ni], 0, 0, 0);
  }

#pragma unroll
  for (int ni = 0; ni < 4; ++ni) {
    const int colb = n0 + wn + 16 * ni;       // uniform per ni
    const int col = colb + l16;
    const float bv = bias[col];
    if (MODE == 0) {
#pragma unroll
      for (int mi = 0; mi < 4; ++mi)
#pragma unroll
        for (int i = 0; i < 4; ++i) {
          const int row = m0 + wm + 16 * mi + quad * 4 + i;
          ((float*)Cout)[(size_t)row * N + col] = acc[mi][ni][i] + bv;
        }
    } else if (colb < 2048) {                 // Q or K part
#pragma unroll
      for (int mi = 0; mi < 4; ++mi)
#pragma unroll
        for (int i = 0; i < 4; ++i) {
          const int row = m0 + wm + 16 * mi + quad * 4 + i;
          ((unsigned short*)Cout)[(size_t)row * N + col] = f2bf(acc[mi][ni][i] + bv);
        }
    } else {                                  // V part -> vT[bh][d][t]
      const int h = (col - 2048) >> 6, d = col & 63;
#pragma unroll
      for (int mi = 0; mi < 4; ++mi)
#pragma unroll
        for (int i = 0; i < 4; ++i) {
          const int row = m0 + wm + 16 * mi + quad * 4 + i;
          const int bb = row >> 11, t = row & 2047;
          vT[((size_t)(bb * 16 + h) * 64 + d) * 2048 + t] = f2bf(acc[mi][ni][i] + bv);
        }
    }
  }
}

// --- k2: flash attention, S^T orientation, no-max softmax, 2-way t-split ---
// Block = 4 waves = 2 q-strips x 2 t-parities. Wave: 32 q rows, 1024 keys.
union AttnSmem {
  unsigned short P[4][32][72];   // per-wave P [q][t], pad 64->72 (18432 B)
  float Om[2][64][36];           // merge buffers per q-strip (18432 B)
};

__global__ __launch_bounds__(256, 3) void attn_mfma(
    const unsigned short* __restrict__ qkv,   // [4096][3072] (Q,K parts)
    const unsigned short* __restrict__ vT,    // [32][64][2048]
    unsigned short* __restrict__ attn_out)    // [4096][1024]
{
  __shared__ AttnSmem sm;
  __shared__ float l_buf[2][2][2][16];        // [qs][tpar][mt][l16]

  const int tid = threadIdx.x;
  const int wave = tid >> 6, lane = tid & 63;
  const int l16 = lane & 15, quad = lane >> 4;
  const int qs = wave >> 1;        // q-strip in block
  const int tpar = wave & 1;       // t-split parity
  const int bh = blockIdx.y, b = bh >> 4, h = bh & 15;
  const int s0 = blockIdx.x * 64 + qs * 32;

  const unsigned short* qb = qkv + (size_t)(b * 2048) * 3072 + h * 64;
  const unsigned short* kb = qb + 1024;
  const unsigned short* vb = vT + (size_t)bh * 64 * 2048;
  unsigned short* Pw = &sm.P[wave][0][0];

  // Q frags (B-layout: k=d, n=q)
  bf16x8 qf[2][2];
#pragma unroll
  for (int mt = 0; mt < 2; ++mt)
#pragma unroll
    for (int ks = 0; ks < 2; ++ks)
      qf[mt][ks] = *(const bf16x8*)&qb[(size_t)(s0 + 16 * mt + l16) * 3072 + 32 * ks + quad * 8];

  f32x4 O[2][4] = {};
  float l_part[2] = {0.0f, 0.0f};
  const float SC = 0.125f * 1.44269504f;      // log2(e)/sqrt(64)

  // preload K frags for first tile (A-layout: m=t, k=d)
  bf16x8 kf[4][2];
  {
    const int t0 = tpar * 64;
#pragma unroll
    for (int nt = 0; nt < 4; ++nt)
#pragma unroll
      for (int ks = 0; ks < 2; ++ks)
        kf[nt][ks] = *(const bf16x8*)&kb[(size_t)(t0 + 16 * nt + l16) * 3072 + 32 * ks + quad * 8];
  }

  for (int it = 0; it < 16; ++it) {
    const int tcur = it * 128 + tpar * 64;

    // ---- S^T = K Q^T: sf[nt][mt], C: row=t_loc=quad*4+i, col=q=l16 ----
    f32x4 sf[4][2];
#pragma unroll
    for (int nt = 0; nt < 4; ++nt)
#pragma unroll
      for (int mt = 0; mt < 2; ++mt) {
        f32x4 c = {0.0f, 0.0f, 0.0f, 0.0f};
        c = __builtin_amdgcn_mfma_f32_16x16x32_bf16(kf[nt][0], qf[mt][0], c, 0, 0, 0);
        c = __builtin_amdgcn_mfma_f32_16x16x32_bf16(kf[nt][1], qf[mt][1], c, 0, 0, 0);
        sf[nt][mt] = c;
      }

    // ---- prefetch K for next tile (same parity) ----
    if (it < 15) {
      const int tn = tcur + 128;
#pragma unroll
      for (int nt = 0; nt < 4; ++nt)
#pragma unroll
        for (int ks = 0; ks < 2; ++ks)
          kf[nt][ks] = *(const bf16x8*)&kb[(size_t)(tn + 16 * nt + l16) * 3072 + 32 * ks + quad * 8];
    }

    // ---- V frags for current tile (B-layout: k=t, n=d), in flight over softmax
    bf16x8 vf[2][4];
#pragma unroll
    for (int ts = 0; ts < 2; ++ts)
#pragma unroll
      for (int nd = 0; nd < 4; ++nd)
        vf[ts][nd] = *(const bf16x8*)&vb[(size_t)(16 * nd + l16) * 2048 + tcur + 32 * ts + quad * 8];

    // ---- softmax-lite: p = exp2(s*SC - 8); per-lane l accumulation ----
#pragma unroll
    for (int nt = 0; nt < 4; ++nt)
#pragma unroll
      for (int mt = 0; mt < 2; ++mt) {
        f32x4 p;
#pragma unroll
        for (int i = 0; i < 4; ++i) {
          p[i] = __builtin_amdgcn_exp2f(__builtin_fmaf(sf[nt][mt][i], SC, -8.0f));
          l_part[mt] += p[i];
        }
        // P[q=16mt+l16][t=16nt+quad*4 .. +3] packed b64
        uint2 w;
        w.x = pack_bf2(p[0], p[1]);
        w.y = pack_bf2(p[2], p[3]);
        *(uint2*)&Pw[(size_t)(16 * mt + l16) * 72 + 16 * nt + quad * 4] = w;
      }

    // ---- P A-frags (m=q, k=t) ----
    bf16x8 pf[2][2];
#pragma unroll
    for (int mt = 0; mt < 2; ++mt)
#pragma unroll
      for (int ts = 0; ts < 2; ++ts)
        pf[mt][ts] = *(const bf16x8*)&Pw[(size_t)(16 * mt + l16) * 72 + 32 * ts + quad * 8];

    // ---- O += P V ----
#pragma unroll
    for (int mt = 0; mt < 2; ++mt)
#pragma unroll
      for (int nd = 0; nd < 4; ++nd) {
        O[mt][nd] = __builtin_amdgcn_mfma_f32_16x16x32_bf16(pf[mt][0], vf[0][nd], O[mt][nd], 0, 0, 0);
        O[mt][nd] = __builtin_amdgcn_mfma_f32_16x16x32_bf16(pf[mt][1], vf[1][nd], O[mt][nd], 0, 0, 0);
      }
  }

  // ---- merge t-split partials (summable: shared implicit max) ----
  if (quad == 0) {
    l_buf[qs][tpar][0][l16] = 0.0f;  // placeholder to keep layout simple
  }
  // per-lane partials: lane (quad,l16) holds partial for q=16mt+l16; reduce
  // across quads now to cut LDS traffic to one value per (q,tpar).
  float l_red[2];
#pragma unroll
  for (int mt = 0; mt < 2; ++mt) {
    float v = l_part[mt];
    v += __shfl_xor(v, 16);
    v += __shfl_xor(v, 32);
    l_red[mt] = v;                  // every lane: total-partial for q=16mt+l16
  }
  if (lane < 16) {
    l_buf[qs][tpar][0][lane] = l_red[0];
    l_buf[qs][tpar][1][lane] = l_red[1];
  }
  __syncthreads();                  // P region free; l_buf visible
  if (tpar == 1) {
#pragma unroll
    for (int mt = 0; mt < 2; ++mt)
#pragma unroll
      for (int nd = 0; nd < 4; ++nd)
        *(f32x4*)&sm.Om[qs][lane][(mt * 4 + nd) * 4] = O[mt][nd];
  }
  __syncthreads();
  if (tpar == 0) {
#pragma unroll
    for (int mt = 0; mt < 2; ++mt) {
      const float lt0 = l_buf[qs][0][mt][quad * 4 + 0] + l_buf[qs][1][mt][quad * 4 + 0];
      const float lt1 = l_buf[qs][0][mt][quad * 4 + 1] + l_buf[qs][1][mt][quad * 4 + 1];
      const float lt2 = l_buf[qs][0][mt][quad * 4 + 2] + l_buf[qs][1][mt][quad * 4 + 2];
      const float lt3 = l_buf[qs][0][mt][quad * 4 + 3] + l_buf[qs][1][mt][quad * 4 + 3];
      const float inv[4] = {1.0f / lt0, 1.0f / lt1, 1.0f / lt2, 1.0f / lt3};
#pragma unroll
      for (int nd = 0; nd < 4; ++nd) {
        f32x4 o2 = *(const f32x4*)&sm.Om[qs][lane][(mt * 4 + nd) * 4];
#pragma unroll
        for (int i = 0; i < 4; ++i) {
          const int row = s0 + 16 * mt + quad * 4 + i;
          const float v = (O[mt][nd][i] + o2[i]) * inv[i];
          attn_out[(size_t)(b * 2048 + row) * 1024 + h * 64 + 16 * nd + l16] = f2bf(v);
        }
      }
    }
  }
}

extern "C" void kernel_launch(void* const* d_in, const int* in_sizes, int n_in,
                              void* d_out, int out_size, void* d_ws, size_t ws_size,
                              hipStream_t stream) {
  const float* x     = (const float*)d_in[0];
  const float* W_qkv = (const float*)d_in[1];
  const float* b_qkv = (const float*)d_in[2];
  const float* W_out = (const float*)d_in[3];
  const float* b_out = (const float*)d_in[4];
  float* out = (float*)d_out;

  char* ws = (char*)d_ws;
  unsigned short* x_bf   = (unsigned short*)(ws);              //  8 MB
  unsigned short* Wqkv_t = (unsigned short*)(ws + 8388608);    //  6 MB
  unsigned short* Wout_t = (unsigned short*)(ws + 14680064);   //  2 MB
  unsigned short* qkv_bf = (unsigned short*)(ws + 16777216);   // 24 MB (Q,K used)
  unsigned short* vT     = (unsigned short*)(ws + 41943040);   //  8 MB
  unsigned short* attn_b = (unsigned short*)(ws + 50331648);   //  8 MB

  cvt_f32_bf16<<<2048, 256, 0, stream>>>(x, x_bf, 4096 * 1024);
  transpose_cvt<<<dim3(48, 16), 256, 0, stream>>>(W_qkv, Wqkv_t, 1024, 3072);
  transpose_cvt<<<dim3(16, 16), 256, 0, stream>>>(W_out, Wout_t, 1024, 1024);

  gemm_mfma<1><<<dim3(24, 32), 256, 0, stream>>>(x_bf, Wqkv_t, b_qkv, qkv_bf, vT,
                                                 4096, 3072, 1024);
  attn_mfma<<<dim3(32, 32), 256, 0, stream>>>(qkv_bf, vT, attn_b);
  gemm_mfma<0><<<dim3(8, 32), 256, 0, stream>>>(attn_b, Wout_t, b_out, out, nullptr,
                                                4096, 1024, 1024);
}

// Round 4
// 212.049 us; speedup vs baseline: 4.8977x; 1.2660x over previous
//
#include <hip/hip_runtime.h>

// ---------------------------------------------------------------------------
// MHSA bf16-MFMA pipeline v4: B=2, S=2048, D=1024, H=16, HD=64
//   p1: x f32 -> bf16;  p2/p3: W transposes -> bf16 [N][K]
//   k1: qkv GEMM; Q,K -> qkv_bf row-major, V -> vT[bh][d][t] in epilogue
//   k2: flash attention: block = 128 q rows, K/V tiles double-buffered in
//       LDS via global_load_lds (XOR chunk swizzle), no-max softmax
//   k3: out GEMM -> f32
// Frag layouts (m89/m91): A[m=l16][k=quad*8+j], B[k=quad*8+j][n=l16],
// C: col=l16, row=quad*4+reg.
// ---------------------------------------------------------------------------

typedef short bf16x8 __attribute__((ext_vector_type(8)));
typedef float f32x4 __attribute__((ext_vector_type(4)));

__device__ __forceinline__ unsigned short f2bf(float f) {   // RNE
  unsigned u = __float_as_uint(f);
  u = (u + 0x7fffu + ((u >> 16) & 1u)) >> 16;
  return (unsigned short)u;
}
__device__ __forceinline__ unsigned pack_bf2(float lo, float hi) {
  unsigned a = __float_as_uint(lo) + 0x8000u;
  unsigned b = __float_as_uint(hi) + 0x8000u;
  return __builtin_amdgcn_perm(b, a, 0x07060302);
}
__device__ __forceinline__ void load_lds16(const unsigned short* g, unsigned short* l) {
  __builtin_amdgcn_global_load_lds(
      (const __attribute__((address_space(1))) void*)g,
      (__attribute__((address_space(3))) void*)l, 16, 0, 0);
}

// --- p1: f32 -> bf16 -------------------------------------------------------
__global__ __launch_bounds__(256) void cvt_f32_bf16(
    const float* __restrict__ in, unsigned short* __restrict__ out, int n)
{
  const int i = (blockIdx.x * 256 + threadIdx.x) * 8;
  if (i >= n) return;
  float4 f0 = *(const float4*)(in + i);
  float4 f1 = *(const float4*)(in + i + 4);
  union { unsigned short u[8]; uint4 v; } pk;
  pk.u[0] = f2bf(f0.x); pk.u[1] = f2bf(f0.y); pk.u[2] = f2bf(f0.z); pk.u[3] = f2bf(f0.w);
  pk.u[4] = f2bf(f1.x); pk.u[5] = f2bf(f1.y); pk.u[6] = f2bf(f1.z); pk.u[7] = f2bf(f1.w);
  *(uint4*)(out + i) = pk.v;
}

// --- p2/p3: transpose+cvt: f32 [R][C] -> bf16 [C][R] -----------------------
__global__ __launch_bounds__(256) void transpose_cvt(
    const float* __restrict__ in, unsigned short* __restrict__ out, int R, int C)
{
  __shared__ float tile[64][65];
  const int tid = threadIdx.x;
  const int r0 = blockIdx.y * 64, c0 = blockIdx.x * 64;
  {
    const int rr = tid >> 4;
    const int cc = (tid & 15) * 4;
#pragma unroll
    for (int it = 0; it < 4; ++it) {
      float4 f = *(const float4*)&in[(size_t)(r0 + rr + 16 * it) * C + c0 + cc];
      tile[rr + 16 * it][cc + 0] = f.x;
      tile[rr + 16 * it][cc + 1] = f.y;
      tile[rr + 16 * it][cc + 2] = f.z;
      tile[rr + 16 * it][cc + 3] = f.w;
    }
  }
  __syncthreads();
  {
    const int cr = tid >> 2;
    const int rk = (tid & 3) * 16;
    union { unsigned short u[16]; uint4 v[2]; } pk;
#pragma unroll
    for (int j = 0; j < 16; ++j) pk.u[j] = f2bf(tile[rk + j][cr]);
    uint4* dst = (uint4*)&out[(size_t)(c0 + cr) * R + r0 + rk];
    dst[0] = pk.v[0];
    dst[1] = pk.v[1];
  }
}

// --- k1/k3: GEMM C = A[M,K] @ Bt[N,K]^T + bias -----------------------------
// MODE 0: f32 out. MODE 1: bf16; cols<2048 -> qkv row-major, cols>=2048 (V)
// transposed into vT[bh][d][t].
template <int MODE>
__global__ __launch_bounds__(256) void gemm_mfma(
    const unsigned short* __restrict__ A,
    const unsigned short* __restrict__ Bt,
    const float* __restrict__ bias,
    void* __restrict__ Cout, unsigned short* __restrict__ vT,
    int M, int N, int K)
{
  __shared__ unsigned short As[128][32];
  __shared__ unsigned short Bs[128][32];
  const int tid = threadIdx.x;
  const int wave = tid >> 6, lane = tid & 63;
  const int l16 = lane & 15, quad = lane >> 4;
  const int m0 = blockIdx.y * 128, n0 = blockIdx.x * 128;
  const int wm = (wave & 1) * 64, wn = (wave >> 1) * 64;
  const int lr = lane >> 2;
  const int lc = (lane & 3) * 8;

  f32x4 acc[4][4] = {};

  for (int k0 = 0; k0 < K; k0 += 32) {
    __syncthreads();
    load_lds16(&A [(size_t)(m0 + 16 * wave + lr) * K + k0 + lc],      &As[16 * wave][0]);
    load_lds16(&A [(size_t)(m0 + 64 + 16 * wave + lr) * K + k0 + lc], &As[64 + 16 * wave][0]);
    load_lds16(&Bt[(size_t)(n0 + 16 * wave + lr) * K + k0 + lc],      &Bs[16 * wave][0]);
    load_lds16(&Bt[(size_t)(n0 + 64 + 16 * wave + lr) * K + k0 + lc], &Bs[64 + 16 * wave][0]);
    __syncthreads();

    bf16x8 af[4], bfr[4];
#pragma unroll
    for (int mi = 0; mi < 4; ++mi)
      af[mi] = *(const bf16x8*)&As[wm + 16 * mi + l16][quad * 8];
#pragma unroll
    for (int ni = 0; ni < 4; ++ni)
      bfr[ni] = *(const bf16x8*)&Bs[wn + 16 * ni + l16][quad * 8];
#pragma unroll
    for (int mi = 0; mi < 4; ++mi)
#pragma unroll
      for (int ni = 0; ni < 4; ++ni)
        acc[mi][ni] = __builtin_amdgcn_mfma_f32_16x16x32_bf16(
            af[mi], bfr[ni], acc[mi][ni], 0, 0, 0);
  }

#pragma unroll
  for (int ni = 0; ni < 4; ++ni) {
    const int colb = n0 + wn + 16 * ni;
    const int col = colb + l16;
    const float bv = bias[col];
    if (MODE == 0) {
#pragma unroll
      for (int mi = 0; mi < 4; ++mi)
#pragma unroll
        for (int i = 0; i < 4; ++i) {
          const int row = m0 + wm + 16 * mi + quad * 4 + i;
          ((float*)Cout)[(size_t)row * N + col] = acc[mi][ni][i] + bv;
        }
    } else if (colb < 2048) {
#pragma unroll
      for (int mi = 0; mi < 4; ++mi)
#pragma unroll
        for (int i = 0; i < 4; ++i) {
          const int row = m0 + wm + 16 * mi + quad * 4 + i;
          ((unsigned short*)Cout)[(size_t)row * N + col] = f2bf(acc[mi][ni][i] + bv);
        }
    } else {
      const int h = (col - 2048) >> 6, d = col & 63;
#pragma unroll
      for (int mi = 0; mi < 4; ++mi)
#pragma unroll
        for (int i = 0; i < 4; ++i) {
          const int row = m0 + wm + 16 * mi + quad * 4 + i;
          const int bb = row >> 11, t = row & 2047;
          vT[((size_t)(bb * 16 + h) * 64 + d) * 2048 + t] = f2bf(acc[mi][ni][i] + bv);
        }
    }
  }
}

// --- k2: flash attention, LDS-staged K/V, swizzled, no-max softmax ---------
// Block = 4 waves; wave w: q rows [bx*128 + 32w, +32), all 2048 keys.
// K/V tiles (64x64 bf16) double-buffered in LDS via global_load_lds.
// Swizzle: LDS chunk c (16B) of row r holds global chunk c ^ (r&7).
// P per wave [32 q][64 t], 8B-granule g at position g ^ (2*(q&7)).
__global__ __launch_bounds__(256, 2) void attn_mfma(
    const unsigned short* __restrict__ qkv,   // [4096][3072] (Q,K used)
    const unsigned short* __restrict__ vT,    // [32][64][2048]
    unsigned short* __restrict__ attn_out)    // [4096][1024]
{
  __shared__ unsigned short Ks[2][4096];
  __shared__ unsigned short Vs[2][4096];
  __shared__ unsigned short Pl[4][2048];

  const int tid = threadIdx.x;
  const int wave = tid >> 6, lane = tid & 63;
  const int l16 = lane & 15, quad = lane >> 4;
  const int bh = blockIdx.y, b = bh >> 4, h = bh & 15;
  const int s0 = blockIdx.x * 128 + wave * 32;

  const unsigned short* qb = qkv + (size_t)(b * 2048) * 3072 + h * 64;
  const unsigned short* kb = qb + 1024;
  const unsigned short* vb = vT + (size_t)bh * 64 * 2048;
  unsigned short* Pw = Pl[wave];

  // staging geometry: instr j of wave w covers rows w*16 + 8j + (lane>>3)
  const int srow = lane >> 3;                     // 0..7
  const int schunk = ((lane & 7) ^ srow) * 8;     // swizzled 16B chunk, shorts
  const int r0a = wave * 16;
  const unsigned short* kg0 = kb + (size_t)(r0a + srow) * 3072 + schunk;
  const unsigned short* kg1 = kg0 + (size_t)8 * 3072;
  const unsigned short* vg0 = vb + (size_t)(r0a + srow) * 2048 + schunk;
  const unsigned short* vg1 = vg0 + (size_t)8 * 2048;

#define STAGE_KV(buf, t0)                                            \
  do {                                                               \
    load_lds16(kg0 + (size_t)(t0) * 3072, &Ks[buf][r0a * 64]);       \
    load_lds16(kg1 + (size_t)(t0) * 3072, &Ks[buf][(r0a + 8) * 64]); \
    load_lds16(vg0 + (t0),                &Vs[buf][r0a * 64]);       \
    load_lds16(vg1 + (t0),                &Vs[buf][(r0a + 8) * 64]); \
  } while (0)

  STAGE_KV(0, 0);

  // Q frags (B-layout: k=d, n=q), from global once
  bf16x8 qf[2][2];
#pragma unroll
  for (int mt = 0; mt < 2; ++mt)
#pragma unroll
    for (int ks = 0; ks < 2; ++ks)
      qf[mt][ks] = *(const bf16x8*)&qb[(size_t)(s0 + 16 * mt + l16) * 3072 + 32 * ks + quad * 8];

  f32x4 O[2][4] = {};
  float l_part[2] = {0.0f, 0.0f};
  const float SC = 0.125f * 1.44269504f;          // log2(e)/sqrt(64)
  const int sw = l16 & 7;                         // K/V read swizzle
  const int psw = 2 * (l16 & 7);                  // P granule swizzle

  for (int it = 0; it < 32; ++it) {
    const int cur = it & 1;
    __syncthreads();                  // drains staging of buf[cur]; prev compute done
    if (it < 31) STAGE_KV(1 - cur, (it + 1) * 64);

    // ---- K frags (A-layout: m=t, k=d) from swizzled LDS ----
    bf16x8 kf[4][2];
#pragma unroll
    for (int nt = 0; nt < 4; ++nt) {
      const int rb = (16 * nt + l16) * 64;
      kf[nt][0] = *(const bf16x8*)&Ks[cur][rb + ((quad ^ sw) * 8)];
      kf[nt][1] = *(const bf16x8*)&Ks[cur][rb + (((4 + quad) ^ sw) * 8)];
    }

    // ---- S^T = K Q^T: C row=t_loc=quad*4+i, col=q=l16 ----
    f32x4 sf[4][2];
#pragma unroll
    for (int nt = 0; nt < 4; ++nt)
#pragma unroll
      for (int mt = 0; mt < 2; ++mt) {
        f32x4 c = {0.0f, 0.0f, 0.0f, 0.0f};
        c = __builtin_amdgcn_mfma_f32_16x16x32_bf16(kf[nt][0], qf[mt][0], c, 0, 0, 0);
        c = __builtin_amdgcn_mfma_f32_16x16x32_bf16(kf[nt][1], qf[mt][1], c, 0, 0, 0);
        sf[nt][mt] = c;
      }

    // ---- V frags (B-layout: k=t, n=d) ----
    bf16x8 vf[2][4];
#pragma unroll
    for (int nd = 0; nd < 4; ++nd) {
      const int rb = (16 * nd + l16) * 64;
      vf[0][nd] = *(const bf16x8*)&Vs[cur][rb + ((quad ^ sw) * 8)];
      vf[1][nd] = *(const bf16x8*)&Vs[cur][rb + (((4 + quad) ^ sw) * 8)];
    }

    // ---- softmax-lite: p = exp2(s*SC - 8); P -> LDS (swizzled) ----
#pragma unroll
    for (int mt = 0; mt < 2; ++mt) {
      unsigned short* prow = &Pw[(16 * mt + l16) * 64];
#pragma unroll
      for (int nt = 0; nt < 4; ++nt) {
        f32x4 p;
#pragma unroll
        for (int i = 0; i < 4; ++i) {
          p[i] = __builtin_amdgcn_exp2f(__builtin_fmaf(sf[nt][mt][i], SC, -8.0f));
          l_part[mt] += p[i];
        }
        uint2 w;
        w.x = pack_bf2(p[0], p[1]);
        w.y = pack_bf2(p[2], p[3]);
        const int g2 = (4 * nt + quad) ^ psw;     // 8B granule position
        *(uint2*)&prow[g2 * 4] = w;
      }
    }

    // ---- P A-frags (m=q, k=t) ----
    bf16x8 pf[2][2];
#pragma unroll
    for (int mt = 0; mt < 2; ++mt) {
      const unsigned short* prow = &Pw[(16 * mt + l16) * 64];
      pf[mt][0] = *(const bf16x8*)&prow[((2 * quad) ^ psw) * 4];
      pf[mt][1] = *(const bf16x8*)&prow[((8 + 2 * quad) ^ psw) * 4];
    }

    // ---- O += P V ----
#pragma unroll
    for (int mt = 0; mt < 2; ++mt)
#pragma unroll
      for (int nd = 0; nd < 4; ++nd) {
        O[mt][nd] = __builtin_amdgcn_mfma_f32_16x16x32_bf16(pf[mt][0], vf[0][nd], O[mt][nd], 0, 0, 0);
        O[mt][nd] = __builtin_amdgcn_mfma_f32_16x16x32_bf16(pf[mt][1], vf[1][nd], O[mt][nd], 0, 0, 0);
      }
  }

  // ---- l reduction across quads; epilogue ----
  float lv[2];
#pragma unroll
  for (int mt = 0; mt < 2; ++mt) {
    float v = l_part[mt];
    v += __shfl_xor(v, 16);
    v += __shfl_xor(v, 32);
    lv[mt] = v;                       // lane holds l for q = 16mt + l16
  }
#pragma unroll
  for (int mt = 0; mt < 2; ++mt) {
#pragma unroll
    for (int i = 0; i < 4; ++i) {
      const float inv = 1.0f / __shfl(lv[mt], quad * 4 + i);
      const size_t row = (size_t)(b * 2048 + s0 + 16 * mt + quad * 4 + i);
#pragma unroll
      for (int nd = 0; nd < 4; ++nd)
        attn_out[row * 1024 + h * 64 + 16 * nd + l16] = f2bf(O[mt][nd][i] * inv);
    }
  }
#undef STAGE_KV
}

extern "C" void kernel_launch(void* const* d_in, const int* in_sizes, int n_in,
                              void* d_out, int out_size, void* d_ws, size_t ws_size,
                              hipStream_t stream) {
  const float* x     = (const float*)d_in[0];
  const float* W_qkv = (const float*)d_in[1];
  const float* b_qkv = (const float*)d_in[2];
  const float* W_out = (const float*)d_in[3];
  const float* b_out = (const float*)d_in[4];
  float* out = (float*)d_out;

  char* ws = (char*)d_ws;
  unsigned short* x_bf   = (unsigned short*)(ws);              //  8 MB
  unsigned short* Wqkv_t = (unsigned short*)(ws + 8388608);    //  6 MB
  unsigned short* Wout_t = (unsigned short*)(ws + 14680064);   //  2 MB
  unsigned short* qkv_bf = (unsigned short*)(ws + 16777216);   // 24 MB (Q,K used)
  unsigned short* vT     = (unsigned short*)(ws + 41943040);   //  8 MB
  unsigned short* attn_b = (unsigned short*)(ws + 50331648);   //  8 MB

  cvt_f32_bf16<<<2048, 256, 0, stream>>>(x, x_bf, 4096 * 1024);
  transpose_cvt<<<dim3(48, 16), 256, 0, stream>>>(W_qkv, Wqkv_t, 1024, 3072);
  transpose_cvt<<<dim3(16, 16), 256, 0, stream>>>(W_out, Wout_t, 1024, 1024);

  gemm_mfma<1><<<dim3(24, 32), 256, 0, stream>>>(x_bf, Wqkv_t, b_qkv, qkv_bf, vT,
                                                 4096, 3072, 1024);
  attn_mfma<<<dim3(16, 32), 256, 0, stream>>>(qkv_bf, vT, attn_b);
  gemm_mfma<0><<<dim3(8, 32), 256, 0, stream>>>(attn_b, Wout_t, b_out, out, nullptr,
                                                4096, 1024, 1024);
}

// Round 5
// 203.379 us; speedup vs baseline: 5.1064x; 1.0426x over previous
//
#include <hip/hip_runtime.h>

// ---------------------------------------------------------------------------
// MHSA bf16-MFMA pipeline v5: B=2, S=2048, D=1024, H=16, HD=64
//   p1: x f32 -> bf16;  p2/p3: W transposes -> bf16 [N][K]
//   k1: qkv GEMM; Q (pre-scaled by log2e/8), K row-major; V -> vT[bh][d][t]
//   k2: flash attention: S^T via 16x16x32, PV via 16x16x16 with P passed
//       register-direct (C-of-S^T == B-frag identity); l via ones-MFMA
//   k3: out GEMM -> f32
// Frag layouts (m89/m91): x32: A[m=l16][k=quad*8+j], B[k=quad*8+j][n=l16];
// x16: A[m=l16][k=quad*4+j], B[k=quad*4+j][n=l16]; C: col=l16, row=quad*4+i.
// ---------------------------------------------------------------------------

typedef short bf16x8 __attribute__((ext_vector_type(8)));
typedef short bf16x4 __attribute__((ext_vector_type(4)));
typedef float f32x4 __attribute__((ext_vector_type(4)));

#if __has_builtin(__builtin_amdgcn_mfma_f32_16x16x16_bf16)
#define MFMA16(a, b, c) __builtin_amdgcn_mfma_f32_16x16x16_bf16(a, b, c, 0, 0, 0)
#else
#define MFMA16(a, b, c) __builtin_amdgcn_mfma_f32_16x16x16bf16_1k(a, b, c, 0, 0, 0)
#endif

__device__ __forceinline__ unsigned short f2bf(float f) {   // RNE
  unsigned u = __float_as_uint(f);
  u = (u + 0x7fffu + ((u >> 16) & 1u)) >> 16;
  return (unsigned short)u;
}
__device__ __forceinline__ unsigned pack_bf2(float lo, float hi) {
  unsigned a = __float_as_uint(lo) + 0x8000u;
  unsigned b = __float_as_uint(hi) + 0x8000u;
  return __builtin_amdgcn_perm(b, a, 0x07060302);
}
__device__ __forceinline__ void load_lds16(const unsigned short* g, unsigned short* l) {
  __builtin_amdgcn_global_load_lds(
      (const __attribute__((address_space(1))) void*)g,
      (__attribute__((address_space(3))) void*)l, 16, 0, 0);
}

// --- p1: f32 -> bf16 -------------------------------------------------------
__global__ __launch_bounds__(256) void cvt_f32_bf16(
    const float* __restrict__ in, unsigned short* __restrict__ out, int n)
{
  const int i = (blockIdx.x * 256 + threadIdx.x) * 8;
  if (i >= n) return;
  float4 f0 = *(const float4*)(in + i);
  float4 f1 = *(const float4*)(in + i + 4);
  union { unsigned short u[8]; uint4 v; } pk;
  pk.u[0] = f2bf(f0.x); pk.u[1] = f2bf(f0.y); pk.u[2] = f2bf(f0.z); pk.u[3] = f2bf(f0.w);
  pk.u[4] = f2bf(f1.x); pk.u[5] = f2bf(f1.y); pk.u[6] = f2bf(f1.z); pk.u[7] = f2bf(f1.w);
  *(uint4*)(out + i) = pk.v;
}

// --- p2/p3: transpose+cvt: f32 [R][C] -> bf16 [C][R] -----------------------
__global__ __launch_bounds__(256) void transpose_cvt(
    const float* __restrict__ in, unsigned short* __restrict__ out, int R, int C)
{
  __shared__ float tile[64][65];
  const int tid = threadIdx.x;
  const int r0 = blockIdx.y * 64, c0 = blockIdx.x * 64;
  {
    const int rr = tid >> 4;
    const int cc = (tid & 15) * 4;
#pragma unroll
    for (int it = 0; it < 4; ++it) {
      float4 f = *(const float4*)&in[(size_t)(r0 + rr + 16 * it) * C + c0 + cc];
      tile[rr + 16 * it][cc + 0] = f.x;
      tile[rr + 16 * it][cc + 1] = f.y;
      tile[rr + 16 * it][cc + 2] = f.z;
      tile[rr + 16 * it][cc + 3] = f.w;
    }
  }
  __syncthreads();
  {
    const int cr = tid >> 2;
    const int rk = (tid & 3) * 16;
    union { unsigned short u[16]; uint4 v[2]; } pk;
#pragma unroll
    for (int j = 0; j < 16; ++j) pk.u[j] = f2bf(tile[rk + j][cr]);
    uint4* dst = (uint4*)&out[(size_t)(c0 + cr) * R + r0 + rk];
    dst[0] = pk.v[0];
    dst[1] = pk.v[1];
  }
}

// --- k1/k3: GEMM C = A[M,K] @ Bt[N,K]^T + bias -----------------------------
// MODE 0: f32 out. MODE 1: bf16: cols<1024 Q (scaled by log2e/8) row-major,
// 1024..2047 K row-major, >=2048 V transposed into vT[bh][d][t] (packed b32).
template <int MODE>
__global__ __launch_bounds__(256) void gemm_mfma(
    const unsigned short* __restrict__ A,
    const unsigned short* __restrict__ Bt,
    const float* __restrict__ bias,
    void* __restrict__ Cout, unsigned short* __restrict__ vT,
    int M, int N, int K)
{
  __shared__ unsigned short As[128][32];
  __shared__ unsigned short Bs[128][32];
  const int tid = threadIdx.x;
  const int wave = tid >> 6, lane = tid & 63;
  const int l16 = lane & 15, quad = lane >> 4;
  const int m0 = blockIdx.y * 128, n0 = blockIdx.x * 128;
  const int wm = (wave & 1) * 64, wn = (wave >> 1) * 64;
  const int lr = lane >> 2;
  const int lc = (lane & 3) * 8;

  f32x4 acc[4][4] = {};

  for (int k0 = 0; k0 < K; k0 += 32) {
    __syncthreads();
    load_lds16(&A [(size_t)(m0 + 16 * wave + lr) * K + k0 + lc],      &As[16 * wave][0]);
    load_lds16(&A [(size_t)(m0 + 64 + 16 * wave + lr) * K + k0 + lc], &As[64 + 16 * wave][0]);
    load_lds16(&Bt[(size_t)(n0 + 16 * wave + lr) * K + k0 + lc],      &Bs[16 * wave][0]);
    load_lds16(&Bt[(size_t)(n0 + 64 + 16 * wave + lr) * K + k0 + lc], &Bs[64 + 16 * wave][0]);
    __syncthreads();

    bf16x8 af[4], bfr[4];
#pragma unroll
    for (int mi = 0; mi < 4; ++mi)
      af[mi] = *(const bf16x8*)&As[wm + 16 * mi + l16][quad * 8];
#pragma unroll
    for (int ni = 0; ni < 4; ++ni)
      bfr[ni] = *(const bf16x8*)&Bs[wn + 16 * ni + l16][quad * 8];
#pragma unroll
    for (int mi = 0; mi < 4; ++mi)
#pragma unroll
      for (int ni = 0; ni < 4; ++ni)
        acc[mi][ni] = __builtin_amdgcn_mfma_f32_16x16x32_bf16(
            af[mi], bfr[ni], acc[mi][ni], 0, 0, 0);
  }

  const float SCQ = 0.18033688f;   // log2(e)/sqrt(64), folded into Q
#pragma unroll
  for (int ni = 0; ni < 4; ++ni) {
    const int colb = n0 + wn + 16 * ni;
    const int col = colb + l16;
    const float bv = bias[col];
    if (MODE == 0) {
#pragma unroll
      for (int mi = 0; mi < 4; ++mi)
#pragma unroll
        for (int i = 0; i < 4; ++i) {
          const int row = m0 + wm + 16 * mi + quad * 4 + i;
          ((float*)Cout)[(size_t)row * N + col] = acc[mi][ni][i] + bv;
        }
    } else if (colb < 1024) {          // Q: pre-scale for exp2 softmax
#pragma unroll
      for (int mi = 0; mi < 4; ++mi)
#pragma unroll
        for (int i = 0; i < 4; ++i) {
          const int row = m0 + wm + 16 * mi + quad * 4 + i;
          ((unsigned short*)Cout)[(size_t)row * N + col] = f2bf((acc[mi][ni][i] + bv) * SCQ);
        }
    } else if (colb < 2048) {          // K
#pragma unroll
      for (int mi = 0; mi < 4; ++mi)
#pragma unroll
        for (int i = 0; i < 4; ++i) {
          const int row = m0 + wm + 16 * mi + quad * 4 + i;
          ((unsigned short*)Cout)[(size_t)row * N + col] = f2bf(acc[mi][ni][i] + bv);
        }
    } else {                           // V -> vT[bh][d][t], packed pairs in t
      const int h = (col - 2048) >> 6, d = col & 63;
#pragma unroll
      for (int mi = 0; mi < 4; ++mi) {
        const int row = m0 + wm + 16 * mi + quad * 4;   // +i, i=0..3
        const int bb = row >> 11, t = row & 2047;
        unsigned short* dst = &vT[((size_t)(bb * 16 + h) * 64 + d) * 2048 + t];
        *(unsigned*)(dst)     = pack_bf2(acc[mi][ni][0] + bv, acc[mi][ni][1] + bv);
        *(unsigned*)(dst + 2) = pack_bf2(acc[mi][ni][2] + bv, acc[mi][ni][3] + bv);
      }
    }
  }
}

// --- k2: flash attention ---------------------------------------------------
// Block = 4 waves; wave w: q rows [bx*128 + 32w, +32), all 2048 keys.
// K,V tiles (64x64 bf16) double-buffered LDS via global_load_lds, XOR chunk
// swizzle (chunk c of row r at c ^ (r&7)). S^T = K Q^T (x32). PV: O^T =
// V^T P^T (x16) with P frags taken register-direct from S^T output.
// l via ones-A-frag x16 MFMA. No P LDS, no shuffles.
__global__ __launch_bounds__(256, 2) void attn_mfma(
    const unsigned short* __restrict__ qkv,   // [4096][3072] (Q,K used)
    const unsigned short* __restrict__ vT,    // [32][64][2048]
    unsigned short* __restrict__ attn_out)    // [4096][1024]
{
  __shared__ unsigned short Ks[2][4096];
  __shared__ unsigned short Vs[2][4096];

  const int tid = threadIdx.x;
  const int wave = tid >> 6, lane = tid & 63;
  const int l16 = lane & 15, quad = lane >> 4;
  const int bh = blockIdx.y, b = bh >> 4, h = bh & 15;
  const int s0 = blockIdx.x * 128 + wave * 32;

  const unsigned short* qb = qkv + (size_t)(b * 2048) * 3072 + h * 64;
  const unsigned short* kb = qb + 1024;
  const unsigned short* vb = vT + (size_t)bh * 64 * 2048;

  const int srow = lane >> 3;                     // 0..7
  const int schunk = ((lane & 7) ^ srow) * 8;     // swizzled 16B chunk
  const int r0a = wave * 16;
  const unsigned short* kg0 = kb + (size_t)(r0a + srow) * 3072 + schunk;
  const unsigned short* kg1 = kg0 + (size_t)8 * 3072;
  const unsigned short* vg0 = vb + (size_t)(r0a + srow) * 2048 + schunk;
  const unsigned short* vg1 = vg0 + (size_t)8 * 2048;

#define STAGE_KV(buf, t0)                                            \
  do {                                                               \
    load_lds16(kg0 + (size_t)(t0) * 3072, &Ks[buf][r0a * 64]);       \
    load_lds16(kg1 + (size_t)(t0) * 3072, &Ks[buf][(r0a + 8) * 64]); \
    load_lds16(vg0 + (t0),                &Vs[buf][r0a * 64]);       \
    load_lds16(vg1 + (t0),                &Vs[buf][(r0a + 8) * 64]); \
  } while (0)

  STAGE_KV(0, 0);

  // Q frags (x32 B-layout: k=d, n=q); Q already scaled by log2e/8
  bf16x8 qf[2][2];
#pragma unroll
  for (int mt = 0; mt < 2; ++mt)
#pragma unroll
    for (int ks = 0; ks < 2; ++ks)
      qf[mt][ks] = *(const bf16x8*)&qb[(size_t)(s0 + 16 * mt + l16) * 3072 + 32 * ks + quad * 8];

  f32x4 O[2][4] = {};      // O^T accum: [mt][nd], C col=q=l16, row=d local
  f32x4 lacc[2] = {};      // l via ones-MFMA, col=q=l16 (rows replicated)
  const bf16x4 ones4 = {(short)0x3F80, (short)0x3F80, (short)0x3F80, (short)0x3F80};
  const int sw = l16 & 7;
  const int h2 = quad >> 1, h1 = (quad & 1) * 4;  // V b64 sub-chunk decomp

  for (int it = 0; it < 32; ++it) {
    const int cur = it & 1;
    __syncthreads();
    if (it < 31) STAGE_KV(1 - cur, (it + 1) * 64);

    // ---- K frags (x32 A-layout: m=t, k=d) from swizzled LDS ----
    bf16x8 kf[4][2];
#pragma unroll
    for (int nt = 0; nt < 4; ++nt) {
      const int rb = (16 * nt + l16) * 64;
      kf[nt][0] = *(const bf16x8*)&Ks[cur][rb + ((quad ^ sw) * 8)];
      kf[nt][1] = *(const bf16x8*)&Ks[cur][rb + (((4 + quad) ^ sw) * 8)];
    }

    // ---- V frags (x16 A-layout: m=d, k=t chunk c) ----
    bf16x4 vf[4][4];
#pragma unroll
    for (int nd = 0; nd < 4; ++nd) {
      const int rb = (16 * nd + l16) * 64;
#pragma unroll
      for (int c = 0; c < 4; ++c)
        vf[nd][c] = *(const bf16x4*)&Vs[cur][rb + (((2 * c + h2) ^ sw) * 8 + h1)];
    }

    // ---- S^T = K Q^T (x32): C row=t=quad*4+i, col=q=l16 ----
    f32x4 sf[4][2];
#pragma unroll
    for (int nt = 0; nt < 4; ++nt)
#pragma unroll
      for (int mt = 0; mt < 2; ++mt) {
        f32x4 c = {0.0f, 0.0f, 0.0f, 0.0f};
        c = __builtin_amdgcn_mfma_f32_16x16x32_bf16(kf[nt][0], qf[mt][0], c, 0, 0, 0);
        c = __builtin_amdgcn_mfma_f32_16x16x32_bf16(kf[nt][1], qf[mt][1], c, 0, 0, 0);
        sf[nt][mt] = c;
      }

    // ---- p = exp2(s); pack to x16 B-frags (C-layout == B-frag identity) ----
    bf16x4 pp[2][4];
#pragma unroll
    for (int mt = 0; mt < 2; ++mt)
#pragma unroll
      for (int nt = 0; nt < 4; ++nt) {
        const float p0 = __builtin_amdgcn_exp2f(sf[nt][mt][0]);
        const float p1 = __builtin_amdgcn_exp2f(sf[nt][mt][1]);
        const float p2 = __builtin_amdgcn_exp2f(sf[nt][mt][2]);
        const float p3 = __builtin_amdgcn_exp2f(sf[nt][mt][3]);
        uint2 w;
        w.x = pack_bf2(p0, p1);
        w.y = pack_bf2(p2, p3);
        pp[mt][nt] = *(bf16x4*)&w;
      }

    // ---- O^T += V^T P^T (x16); l += ones P^T ----
#pragma unroll
    for (int c = 0; c < 4; ++c)
#pragma unroll
      for (int mt = 0; mt < 2; ++mt) {
        lacc[mt] = MFMA16(ones4, pp[mt][c], lacc[mt]);
#pragma unroll
        for (int nd = 0; nd < 4; ++nd)
          O[mt][nd] = MFMA16(vf[nd][c], pp[mt][c], O[mt][nd]);
      }
  }

  // ---- epilogue: lane holds q=s0+16mt+l16, d=16nd+quad*4+{0..3} ----
#pragma unroll
  for (int mt = 0; mt < 2; ++mt) {
    const float inv = 1.0f / lacc[mt][0];
    const size_t row = (size_t)(b * 2048 + s0 + 16 * mt + l16);
#pragma unroll
    for (int nd = 0; nd < 4; ++nd) {
      uint2 w;
      w.x = pack_bf2(O[mt][nd][0] * inv, O[mt][nd][1] * inv);
      w.y = pack_bf2(O[mt][nd][2] * inv, O[mt][nd][3] * inv);
      *(uint2*)&attn_out[row * 1024 + h * 64 + 16 * nd + quad * 4] = w;
    }
  }
#undef STAGE_KV
}

extern "C" void kernel_launch(void* const* d_in, const int* in_sizes, int n_in,
                              void* d_out, int out_size, void* d_ws, size_t ws_size,
                              hipStream_t stream) {
  const float* x     = (const float*)d_in[0];
  const float* W_qkv = (const float*)d_in[1];
  const float* b_qkv = (const float*)d_in[2];
  const float* W_out = (const float*)d_in[3];
  const float* b_out = (const float*)d_in[4];
  float* out = (float*)d_out;

  char* ws = (char*)d_ws;
  unsigned short* x_bf   = (unsigned short*)(ws);              //  8 MB
  unsigned short* Wqkv_t = (unsigned short*)(ws + 8388608);    //  6 MB
  unsigned short* Wout_t = (unsigned short*)(ws + 14680064);   //  2 MB
  unsigned short* qkv_bf = (unsigned short*)(ws + 16777216);   // 24 MB (Q,K used)
  unsigned short* vT     = (unsigned short*)(ws + 41943040);   //  8 MB
  unsigned short* attn_b = (unsigned short*)(ws + 50331648);   //  8 MB

  cvt_f32_bf16<<<2048, 256, 0, stream>>>(x, x_bf, 4096 * 1024);
  transpose_cvt<<<dim3(48, 16), 256, 0, stream>>>(W_qkv, Wqkv_t, 1024, 3072);
  transpose_cvt<<<dim3(16, 16), 256, 0, stream>>>(W_out, Wout_t, 1024, 1024);

  gemm_mfma<1><<<dim3(24, 32), 256, 0, stream>>>(x_bf, Wqkv_t, b_qkv, qkv_bf, vT,
                                                 4096, 3072, 1024);
  attn_mfma<<<dim3(16, 32), 256, 0, stream>>>(qkv_bf, vT, attn_b);
  gemm_mfma<0><<<dim3(8, 32), 256, 0, stream>>>(attn_b, Wout_t, b_out, out, nullptr,
                                                4096, 1024, 1024);
}